// Round 19
// baseline (125.317 us; speedup 1.0000x reference)
//
#include <hip/hip_runtime.h>
#include <hip/hip_bf16.h>
#include <stdint.h>

// ---------------------------------------------------------------------------
// MHA block: out = softmax( rope(xWq^T) rope(xWk^T)^T / 8 ) (xWv^T) Wo^T
// B=2 S=2048 H=16 D=64 DIM=1024.  bf16 MFMA compute, fp32 accum/softmax.
// ---------------------------------------------------------------------------

#define AS1(p) ((const __attribute__((address_space(1))) void*)(p))
#define AS3(p) ((__attribute__((address_space(3))) void*)(p))

typedef __attribute__((ext_vector_type(8)))  __bf16 bf16x8;
typedef __attribute__((ext_vector_type(4)))  float  f32x4;
typedef __attribute__((ext_vector_type(16))) float  f32x16;

__device__ __forceinline__ ushort f2b(float f) {
  union { float f; uint32_t u; } v; v.f = f;
  uint32_t u = v.u;
  u += 0x7fffu + ((u >> 16) & 1);   // RNE
  return (ushort)(u >> 16);
}
__device__ __forceinline__ float b2f(ushort s) {
  union { uint32_t u; float f; } v; v.u = ((uint32_t)s) << 16;
  return v.f;
}
__device__ __forceinline__ uint32_t pkbf16(float lo, float hi) {
  uint32_t w;
  asm("v_cvt_pk_bf16_f32 %0, %1, %2" : "=v"(w) : "v"(lo), "v"(hi));
  return w;
}
// Fast exp2 via native v_exp_f32.  R10 LESSON: raw inline-asm v_exp_f32 has
// a TRANS->VALU dependent-use hazard the compiler does NOT guard for asm.
// Prefer the builtin; asm fallback carries its own s_nop.
__device__ __forceinline__ float fast_exp2(float x) {
#if __has_builtin(__builtin_amdgcn_exp2f)
  return __builtin_amdgcn_exp2f(x);
#else
  float r;
  asm("v_exp_f32 %0, %1\n\ts_nop 1" : "=v"(r) : "v"(x));
  return r;
#endif
}

// ---------------------------------------------------------------------------
// 1) fp32 -> bf16 conversion of the FOUR WEIGHTS only (x is now staged fp32
//    directly by gemm_qkv); also generates the RoPE cos/sin table.
//    1,048,576 float4s; 2048 blocks x 2-iter grid-stride.
// ---------------------------------------------------------------------------
__global__ __launch_bounds__(256) void cvt_w_k(
    const float* __restrict__ wq, const float* __restrict__ wk,
    const float* __restrict__ wv, const float* __restrict__ wo,
    ushort* __restrict__ dst, float2* __restrict__ tab) {
  for (int it = 0; it < 2; it++) {
    int i = (it * 2048 + blockIdx.x) * 256 + threadIdx.x;  // 1,048,576 total
    const float* src;
    if      (i < 262144) src = wq + (size_t)i * 4;
    else if (i < 524288) src = wk + (size_t)(i - 262144) * 4;
    else if (i < 786432) src = wv + (size_t)(i - 524288) * 4;
    else                 src = wo + (size_t)(i - 786432) * 4;
    float4 v = *(const float4*)src;
    ushort4 o;
    o.x = f2b(v.x); o.y = f2b(v.y); o.z = f2b(v.z); o.w = f2b(v.w);
    ((ushort4*)dst)[i] = o;

    if (i < 65536) {                               // rope table: s x dp
      int s = i >> 5, dp = i & 31;
      float inv = exp2f((float)dp * (-13.2877123795494f / 32.0f));
      float ang = (float)s * inv;
      float sn, cs;
      sincosf(ang, &sn, &cs);
      tab[i] = make_float2(cs, sn);
    }
  }
}

// ---------------------------------------------------------------------------
// 2) bf16 GEMM mainloop (used by gemm_out): C = A(MxK)*W(NxK)^T, 128x128
//    tile, BK=32, 4 waves, dbuf LDS, single barrier/K-step (R16 form).
// ---------------------------------------------------------------------------
__device__ __forceinline__ void gemm_mainloop(
    const ushort* __restrict__ A, const ushort* __restrict__ W,
    int row0, int col0, ushort* lds, f32x4 acc[4][4]) {
  const int K = 1024;
  int tid = threadIdx.x;
  int lane = tid & 63, wid = tid >> 6;
  int wr = wid >> 1, wc = wid & 1;
  int lr = lane >> 4, lc = lane & 15;
  ushort* lA = lds;
  ushort* lB = lds + 8192;

  auto stage = [&](int buf, int k0) {
#pragma unroll
    for (int i = 0; i < 2; i++) {
      int idx = tid + i * 256;                       // 16B chunk id, 4 per row
      const ushort* ga = A + (size_t)(row0 + (idx >> 2)) * K + k0 + (idx & 3) * 8;
      __builtin_amdgcn_global_load_lds(AS1(ga),
          AS3(lA + buf * 4096 + (i * 256 + wid * 64) * 8), 16, 0, 0);
      const ushort* gb = W + (size_t)(col0 + (idx >> 2)) * K + k0 + (idx & 3) * 8;
      __builtin_amdgcn_global_load_lds(AS1(gb),
          AS3(lB + buf * 4096 + (i * 256 + wid * 64) * 8), 16, 0, 0);
    }
  };

  stage(0, 0);
  __syncthreads();
  int cur = 0;
  for (int k0 = 0; k0 < K; k0 += 32) {
    if (k0 + 32 < K) stage(cur ^ 1, k0 + 32);
    const ushort* a  = lA + cur * 4096;
    const ushort* bm = lB + cur * 4096;
    bf16x8 af[4], bfr[4];
#pragma unroll
    for (int m = 0; m < 4; m++)
      af[m] = *(const bf16x8*)(a + (wr * 64 + m * 16 + lc) * 32 + lr * 8);
#pragma unroll
    for (int n = 0; n < 4; n++)
      bfr[n] = *(const bf16x8*)(bm + (wc * 64 + n * 16 + lc) * 32 + lr * 8);
#pragma unroll
    for (int m = 0; m < 4; m++)
#pragma unroll
      for (int n = 0; n < 4; n++)
        acc[m][n] = __builtin_amdgcn_mfma_f32_16x16x32_bf16(af[m], bfr[n], acc[m][n], 0, 0, 0);
    __syncthreads();     // drains: my ds_reads + next-buffer gload_lds writes
    cur ^= 1;
  }
}

// ---------------------------------------------------------------------------
// QKV projections (z = 0:Q, 1:K, 2:V).  A = x staged as FP32 (16B chunks,
// XOR-swizzled: chunk ^= row&7, pre-swizzled global source) and converted
// to bf16 at fragment-load time (4 cvt_pk per frag; VALU is idle here).
// B = weights bf16 (from cvt_w).  LDS: A dbuf 32K + B dbuf 16K = 48 KB.
// Q,K -> [B,H,S,D] with FUSED ROPE; V -> [B,H,D,S] via LDS transpose.
// ---------------------------------------------------------------------------
__global__ __launch_bounds__(256) void gemm_qkv_k(
    const float* __restrict__ x,
    const ushort* __restrict__ wqb, const ushort* __restrict__ wkb,
    const ushort* __restrict__ wvb,
    const float2* __restrict__ tab,
    ushort* __restrict__ Qb, ushort* __restrict__ Kb, ushort* __restrict__ Vtb) {
  __shared__ char ldsq[49152];         // A fp32 dbuf 32K | B bf16 dbuf 16K
  const int K = 1024;
  int z = blockIdx.z;
  const ushort* w = (z == 0) ? wqb : (z == 1) ? wkb : wvb;
  int row0 = blockIdx.x * 128, col0 = blockIdx.y * 128;
  int tid = threadIdx.x, lane = tid & 63, wid = tid >> 6;
  int wr = wid >> 1, wc = wid & 1, lr = lane >> 4, lc = lane & 15;
  ushort* lB = (ushort*)(ldsq + 32768);

  auto stage = [&](int buf, int k0) {
    // A: [128 rows][32 k] fp32 = 1024 16B-chunks; 4 per thread.
    // chunk c: row=c>>3, cp=c&7; source pre-swizzled (cp^(row&7)).
#pragma unroll
    for (int i = 0; i < 4; i++) {
      int c = i * 256 + tid;
      int r = c >> 3, cp = c & 7;
      const float* ga = x + (size_t)(row0 + r) * K + k0 + ((cp ^ (r & 7)) << 2);
      __builtin_amdgcn_global_load_lds(AS1(ga),
          AS3(ldsq + buf * 16384 + (i * 256 + wid * 64) * 16), 16, 0, 0);
    }
    // B: [128 rows][32 k] bf16 = 512 chunks; 2 per thread (linear).
#pragma unroll
    for (int i = 0; i < 2; i++) {
      int idx = tid + i * 256;
      const ushort* gb = w + (size_t)(col0 + (idx >> 2)) * K + k0 + (idx & 3) * 8;
      __builtin_amdgcn_global_load_lds(AS1(gb),
          AS3(lB + buf * 4096 + (i * 256 + wid * 64) * 8), 16, 0, 0);
    }
  };

  f32x4 acc[4][4] = {};
  stage(0, 0);
  __syncthreads();
  int cur = 0;
  for (int k0 = 0; k0 < K; k0 += 32) {
    if (k0 + 32 < K) stage(cur ^ 1, k0 + 32);
    const char* a = ldsq + cur * 16384;
    const ushort* bm = lB + cur * 4096;
    bf16x8 af[4], bfr[4];
#pragma unroll
    for (int m = 0; m < 4; m++) {
      int r = wr * 64 + m * 16 + lc;                 // r&7 == lc&7
      float4 lo = *(const float4*)(a + r * 128 + (((2 * lr)     ^ (lc & 7)) << 4));
      float4 hi = *(const float4*)(a + r * 128 + (((2 * lr + 1) ^ (lc & 7)) << 4));
      union { uint32_t u[4]; bf16x8 v; } t;
      t.u[0] = pkbf16(lo.x, lo.y); t.u[1] = pkbf16(lo.z, lo.w);
      t.u[2] = pkbf16(hi.x, hi.y); t.u[3] = pkbf16(hi.z, hi.w);
      af[m] = t.v;
    }
#pragma unroll
    for (int n = 0; n < 4; n++)
      bfr[n] = *(const bf16x8*)(bm + (wc * 64 + n * 16 + lc) * 32 + lr * 8);
#pragma unroll
    for (int m = 0; m < 4; m++)
#pragma unroll
      for (int n = 0; n < 4; n++)
        acc[m][n] = __builtin_amdgcn_mfma_f32_16x16x32_bf16(af[m], bfr[n], acc[m][n], 0, 0, 0);
    __syncthreads();
    cur ^= 1;
  }

  if (z < 2) {
    ushort* dst = (z == 0) ? Qb : Kb;
    const float qs = (z == 0) ? 0.125f * 1.44269504088896f : 1.0f;
#pragma unroll
    for (int m = 0; m < 4; m++)
#pragma unroll
      for (int n = 0; n < 2; n++)
#pragma unroll
        for (int j = 0; j < 4; j++) {
          int i = row0 + wr * 64 + m * 16 + lr * 4 + j;   // row: b,s
          int c = col0 + wc * 64 + n * 16 + lc;           // col: h,d (d<32)
          int b = i >> 11, s = i & 2047, h = c >> 6, dp = c & 31;
          float2 cs = tab[s * 32 + dp];
          float q1 = acc[m][n][j], q2 = acc[m][n + 2][j];
          float r1 = (q1 * cs.x - q2 * cs.y) * qs;
          float r2 = (q2 * cs.x + q1 * cs.y) * qs;
          size_t base = (size_t)(b * 16 + h) * 131072 + (size_t)s * 64;
          dst[base + dp]      = f2b(r1);
          dst[base + dp + 32] = f2b(r2);
        }
  } else {
    // V: transpose 128x128 tile through LDS (A region free after barrier).
    ushort* vls = (ushort*)ldsq;
#pragma unroll
    for (int m = 0; m < 4; m++)
#pragma unroll
      for (int n = 0; n < 4; n++) {
        int c = wc * 64 + n * 16 + lc;
        int sb = wr * 64 + m * 16 + lr * 4;            // j=0..3 consecutive
        uint32_t w0 = pkbf16(acc[m][n][0], acc[m][n][1]);
        uint32_t w1 = pkbf16(acc[m][n][2], acc[m][n][3]);
        int soff = sb ^ ((c & 7) << 3);                // multiple of 4 ushorts
        uint2 val; val.x = w0; val.y = w1;
        *(uint2*)(vls + c * 128 + soff) = val;         // 8B store
      }
    __syncthreads();
    int b = row0 >> 11, srow = row0 & 2047;
#pragma unroll
    for (int i = 0; i < 8; i++) {
      int idx = i * 256 + tid;                 // 2048 16B chunks
      int cl = idx >> 4, sc = idx & 15;
      int soff = (sc * 8) ^ ((cl & 7) << 3);
      bf16x8 v = *(const bf16x8*)(vls + cl * 128 + soff);
      int cg = col0 + cl, h = cg >> 6, d = cg & 63;
      *(bf16x8*)(Vtb + (size_t)(b * 16 + h) * 131072 + (size_t)d * 2048 + srow + sc * 8) = v;
    }
  }
}

// Final projection: out(fp32) = attn @ Wo^T.  128x64 tile, 512 blocks
// (2 blocks/CU), R16 single-barrier dbuf form.
__global__ __launch_bounds__(256) void gemm_out_k(
    const ushort* __restrict__ Ab, const ushort* __restrict__ wob,
    float* __restrict__ out) {
  __shared__ ushort lds[12288];   // lA dbuf 2x[128][32], lB dbuf 2x[64][32]
  const int K = 1024;
  int tid = threadIdx.x, lane = tid & 63, wid = tid >> 6;
  int lr = lane >> 4, lc = lane & 15;
  int row0 = blockIdx.x * 128, col0 = blockIdx.y * 64;
  ushort* lA = lds;
  ushort* lB = lds + 8192;

  auto stage = [&](int buf, int k0) {
#pragma unroll
    for (int i = 0; i < 2; i++) {
      int idx = tid + i * 256;                       // A: 512 chunks, 4/row
      const ushort* ga = Ab + (size_t)(row0 + (idx >> 2)) * K + k0 + (idx & 3) * 8;
      __builtin_amdgcn_global_load_lds(AS1(ga),
          AS3(lA + buf * 4096 + (i * 256 + wid * 64) * 8), 16, 0, 0);
    }
    const ushort* gb = wob + (size_t)(col0 + (tid >> 2)) * K + k0 + (tid & 3) * 8;
    __builtin_amdgcn_global_load_lds(AS1(gb),
        AS3(lB + buf * 2048 + wid * 512), 16, 0, 0);
  };

  f32x4 acc[2][4] = {};
  stage(0, 0);
  __syncthreads();
  int cur = 0;
  for (int k0 = 0; k0 < K; k0 += 32) {
    if (k0 + 32 < K) stage(cur ^ 1, k0 + 32);
    const ushort* a  = lA + cur * 4096;
    const ushort* bm = lB + cur * 2048;
    bf16x8 af[2], bfr[4];
#pragma unroll
    for (int m = 0; m < 2; m++)
      af[m] = *(const bf16x8*)(a + (wid * 32 + m * 16 + lc) * 32 + lr * 8);
#pragma unroll
    for (int n = 0; n < 4; n++)
      bfr[n] = *(const bf16x8*)(bm + (n * 16 + lc) * 32 + lr * 8);
#pragma unroll
    for (int m = 0; m < 2; m++)
#pragma unroll
      for (int n = 0; n < 4; n++)
        acc[m][n] = __builtin_amdgcn_mfma_f32_16x16x32_bf16(af[m], bfr[n], acc[m][n], 0, 0, 0);
    __syncthreads();
    cur ^= 1;
  }

  int base_r = row0 + wid * 32;
#pragma unroll
  for (int m = 0; m < 2; m++)
#pragma unroll
    for (int n = 0; n < 4; n++)
#pragma unroll
      for (int j = 0; j < 4; j++) {
        int i = base_r + m * 16 + lr * 4 + j;
        int c = col0 + n * 16 + lc;
        out[(size_t)i * 1024 + c] = acc[m][n][j];
      }
}

// ---------------------------------------------------------------------------
// 3) Flash attention, 32x32 swapped-QK + within-block KV-split + counted
//    vmcnt pipeline + intra-iteration MFMA/VALU interleave (unchanged).
// ---------------------------------------------------------------------------
__global__ __launch_bounds__(512, 4) void attn_k(
    const ushort* __restrict__ Qb, const ushort* __restrict__ Kb,
    const ushort* __restrict__ Vtb, ushort* __restrict__ Ob) {
  __shared__ char ldsb[65536];   // [buf:2][tile:2][K 8KB | V 8KB]; reused
  int tid = threadIdx.x, lane = tid & 63, wid = tid >> 6;   // wid in [0,8)
  int lc5 = lane & 31, hi = lane >> 5;
  int qsub = wid & 3, grp = wid >> 2;

  // XCD swizzle: all q-tiles of a head on one XCD
  int bid = blockIdx.x;
  int qt = (bid >> 3) & 15;
  int bh = (bid & 7) + ((bid >> 7) << 3);
  int q0 = qt * 128 + qsub * 32;
  const ushort* Qp = Qb  + (size_t)bh * 131072 + (size_t)q0 * 64;
  const ushort* Kp = Kb  + (size_t)bh * 131072;
  const ushort* Vp = Vtb + (size_t)bh * 131072;

  // Q as B-operand: col = q = lc5, k-dim = d: slice ks -> d = ks*16+8*hi+i
  bf16x8 qf[4];
#pragma unroll
  for (int ks = 0; ks < 4; ks++)
    qf[ks] = *(const bf16x8*)(Qp + lc5 * 64 + ks * 16 + hi * 8);

  f32x16 o0, o1;
#pragma unroll
  for (int i = 0; i < 16; i++) { o0[i] = 0.f; o1[i] = 0.f; }
  float lsum = 0.f;

  // swizzled in-row chunk offsets: chunk(ks) = (2ks+hi) ^ (row&7), row&7=lc5&7
  int swz[4];
#pragma unroll
  for (int ks = 0; ks < 4; ks++)
    swz[ks] = (((2 * ks + hi) ^ (lc5 & 7)) << 4);
  const int rbase = lc5 * 128;

  // stage the 128-key pair [kvp, kvp+128) into buf: tile t = keys
  // [kvp+64t, kvp+64t+64).  4 gload_lds per thread per call.
  auto stage = [&](int buf, int kvp) {
    int r = tid >> 3, cp = tid & 7;
    int ubase = wid * 1024;
#pragma unroll
    for (int t = 0; t < 2; t++) {
      char* tb = ldsb + buf * 32768 + t * 16384;
      const ushort* gk = Kp + (size_t)(kvp + 64 * t + r) * 64 + ((cp ^ (r & 7)) << 3);
      __builtin_amdgcn_global_load_lds(AS1(gk), AS3(tb + ubase), 16, 0, 0);
      const ushort* gv = Vp + (size_t)r * 2048 + kvp + 64 * t + ((cp ^ (r & 7)) << 3);
      __builtin_amdgcn_global_load_lds(AS1(gv), AS3(tb + 8192 + ubase), 16, 0, 0);
    }
  };

  // softmax + pack one 32-key half: exp2, row-sum accumulate, -> 2 A-frags
  auto smpack = [&](f32x16& s, bf16x8* aout) {
#pragma unroll
    for (int i = 0; i < 16; i++) s[i] = fast_exp2(s[i]);
    float acc = 0.f;
#pragma unroll
    for (int i = 0; i < 16; i++) acc += s[i];
    lsum += acc;
#pragma unroll
    for (int h2 = 0; h2 < 2; h2++) {
      int rb = 8 * h2;
      uint32_t wa1 = pkbf16(s[rb],     s[rb + 1]);
      uint32_t wb1 = pkbf16(s[rb + 4], s[rb + 5]);
      asm("v_permlane32_swap_b32 %0, %1" : "+v"(wa1), "+v"(wb1));
      uint32_t wa2 = pkbf16(s[rb + 2], s[rb + 3]);
      uint32_t wb2 = pkbf16(s[rb + 6], s[rb + 7]);
      asm("v_permlane32_swap_b32 %0, %1" : "+v"(wa2), "+v"(wb2));
      union { uint32_t u[4]; bf16x8 v; } tmp;
      tmp.u[0] = wa1; tmp.u[1] = wa2; tmp.u[2] = wb1; tmp.u[3] = wb2;
      aout[h2] = tmp.v;
    }
  };

  stage(0, 0);      // pair 0 -> buf 0   (4 loads)
  stage(1, 128);    // pair 1 -> buf 1   (4 loads)
  int cur = 0;

  for (int kvp = 0; kvp < 2048; kvp += 128) {
    // wait MY pair-p loads (oldest 4); keep pair-(p+1)'s 4 in flight
    if (kvp + 128 < 2048) asm volatile("s_waitcnt vmcnt(4)" ::: "memory");
    else                  asm volatile("s_waitcnt vmcnt(0)" ::: "memory");
    asm volatile("s_barrier" ::: "memory");   // pair-p writes visible block-wide

    const char* kbuf = ldsb + cur * 32768 + grp * 16384;   // my tile
    const char* vbuf = kbuf + 8192;

    // --- QK chains: s0 fully first, then s1 (independent chains) ---
    f32x16 s0 = {}, s1 = {};
    __builtin_amdgcn_s_setprio(1);
#pragma unroll
    for (int ks = 0; ks < 4; ks++) {
      bf16x8 ka0 = *(const bf16x8*)(kbuf + rbase + swz[ks]);
      s0 = __builtin_amdgcn_mfma_f32_32x32x16_bf16(ka0, qf[ks], s0, 0, 0, 0);
    }
#pragma unroll
    for (int ks = 0; ks < 4; ks++) {
      bf16x8 ka1 = *(const bf16x8*)(kbuf + 4096 + rbase + swz[ks]);
      s1 = __builtin_amdgcn_mfma_f32_32x32x16_bf16(ka1, qf[ks], s1, 0, 0, 0);
    }
    __builtin_amdgcn_s_setprio(0);

    // --- softmax(s0): VALU overlaps s1's in-flight MFMAs ---
    bf16x8 a01[2], a23[2];
    smpack(s0, a01);

    // --- PV ks=0,1 (uses only a01): MFMA overlaps softmax(s1) below ---
    __builtin_amdgcn_s_setprio(1);
#pragma unroll
    for (int ks = 0; ks < 2; ks++) {
      bf16x8 vb0 = *(const bf16x8*)(vbuf + rbase + swz[ks]);
      bf16x8 vb1 = *(const bf16x8*)(vbuf + 4096 + rbase + swz[ks]);
      o0 = __builtin_amdgcn_mfma_f32_32x32x16_bf16(a01[ks], vb0, o0, 0, 0, 0);
      o1 = __builtin_amdgcn_mfma_f32_32x32x16_bf16(a01[ks], vb1, o1, 0, 0, 0);
    }
    __builtin_amdgcn_s_setprio(0);

    // --- softmax(s1): VALU overlaps PV ks=0,1 ---
    smpack(s1, a23);

    // --- PV ks=2,3 ---
    __builtin_amdgcn_s_setprio(1);
#pragma unroll
    for (int ks = 2; ks < 4; ks++) {
      bf16x8 vb0 = *(const bf16x8*)(vbuf + rbase + swz[ks]);
      bf16x8 vb1 = *(const bf16x8*)(vbuf + 4096 + rbase + swz[ks]);
      o0 = __builtin_amdgcn_mfma_f32_32x32x16_bf16(a23[ks - 2], vb0, o0, 0, 0, 0);
      o1 = __builtin_amdgcn_mfma_f32_32x32x16_bf16(a23[ks - 2], vb1, o1, 0, 0, 0);
    }
    __builtin_amdgcn_s_setprio(0);

    asm volatile("s_barrier" ::: "memory");   // all waves done reading buf cur
    if (kvp + 256 < 2048) stage(cur, kvp + 256);   // overwrite freed buffer
    cur ^= 1;
  }

  // combine the two kv-halves: group 1 writes partials, group 0 adds.
  // stride 33 floats (odd) -> conflict-free.  ldsb free: vmcnt drained at
  // last iter, all reads done at its trailing barrier.
  float* cb = (float*)ldsb;
  float* p = cb + (size_t)(qsub * 64 + lane) * 33;
  if (grp == 1) {
#pragma unroll
    for (int i = 0; i < 16; i++) { p[i] = o0[i]; p[16 + i] = o1[i]; }
    p[32] = lsum;
  }
  __syncthreads();
  if (grp == 0) {
#pragma unroll
    for (int i = 0; i < 16; i++) { o0[i] += p[i]; o1[i] += p[16 + i]; }
    lsum += p[32];

    // combine the two key-halves of lsum (lanes q and q+32), then normalize
    lsum += __shfl_xor(lsum, 32);
    float invq = 1.0f / lsum;
    float invr[16];
#pragma unroll
    for (int r = 0; r < 16; r++)
      invr[r] = __shfl(invq, (r & 3) + 8 * (r >> 2) + 4 * hi);

    int b = bh >> 4, h = bh & 15;
    ushort* Op = Ob + (size_t)(b * 2048 + q0) * 1024 + h * 64 + lc5;
#pragma unroll
    for (int r = 0; r < 16; r++) {
      int rrow = (r & 3) + 8 * (r >> 2) + 4 * hi;
      Op[(size_t)rrow * 1024]      = f2b(o0[r] * invr[r]);
      Op[(size_t)rrow * 1024 + 32] = f2b(o1[r] * invr[r]);
    }
  }
}

// ---------------------------------------------------------------------------
// Workspace layout: wqb/wkb/wvb/wob 2M each (0..8M) | Qb 8M | Kb 8M |
// Vtb 8M | Ob 8M  (total 40 MiB).  x is read fp32 directly from d_in.
// The rope cos/sin table (512 KB) borrows the head of the Ob region.
// ---------------------------------------------------------------------------
extern "C" void kernel_launch(void* const* d_in, const int* in_sizes, int n_in,
                              void* d_out, int out_size, void* d_ws, size_t ws_size,
                              hipStream_t stream) {
  const float* x  = (const float*)d_in[0];
  const float* wq = (const float*)d_in[1];
  const float* wk = (const float*)d_in[2];
  const float* wv = (const float*)d_in[3];
  const float* wo = (const float*)d_in[4];
  float* out = (float*)d_out;
  char* ws = (char*)d_ws;
  const size_t MiB = 1024 * 1024;
  ushort* wqb = (ushort*)(ws + 0);
  ushort* wkb = (ushort*)(ws + 2 * MiB);
  ushort* wvb = (ushort*)(ws + 4 * MiB);
  ushort* wob = (ushort*)(ws + 6 * MiB);
  ushort* Qb  = (ushort*)(ws + 8 * MiB);
  ushort* Kb  = (ushort*)(ws + 16 * MiB);
  ushort* Vtb = (ushort*)(ws + 24 * MiB);
  ushort* Ob  = (ushort*)(ws + 32 * MiB);
  float2* tab = (float2*)Ob;                 // 512 KB, transient (cvt->qkv)

  cvt_w_k<<<2048, 256, 0, stream>>>(wq, wk, wv, wo, wqb, tab);
  dim3 gqkv(32, 8, 3);
  gemm_qkv_k<<<gqkv, 256, 0, stream>>>(x, wqb, wkb, wvb, tab, Qb, Kb, Vtb);
  attn_k<<<512, 512, 0, stream>>>(Qb, Kb, Vtb, Ob);
  dim3 gout(32, 16);
  gemm_out_k<<<gout, 256, 0, stream>>>(Ob, wob, out);
}

// Round 20
// 101.872 us; speedup vs baseline: 1.2302x; 1.2302x over previous
//
#include <hip/hip_runtime.h>
#include <hip/hip_bf16.h>
#include <stdint.h>

// ---------------------------------------------------------------------------
// MHA block: out = softmax( rope(xWq^T) rope(xWk^T)^T / 8 ) (xWv^T) Wo^T
// B=2 S=2048 H=16 D=64 DIM=1024.  bf16 MFMA compute, fp32 accum/softmax.
// R20 = exact restore of the R18 best (102.2 us).  R19's fp32-x staging
// regressed (conversion moved onto the per-K-step operand path).
// ---------------------------------------------------------------------------

#define AS1(p) ((const __attribute__((address_space(1))) void*)(p))
#define AS3(p) ((__attribute__((address_space(3))) void*)(p))

typedef __attribute__((ext_vector_type(8)))  __bf16 bf16x8;
typedef __attribute__((ext_vector_type(4)))  float  f32x4;
typedef __attribute__((ext_vector_type(16))) float  f32x16;

__device__ __forceinline__ ushort f2b(float f) {
  union { float f; uint32_t u; } v; v.f = f;
  uint32_t u = v.u;
  u += 0x7fffu + ((u >> 16) & 1);   // RNE
  return (ushort)(u >> 16);
}
__device__ __forceinline__ float b2f(ushort s) {
  union { uint32_t u; float f; } v; v.u = ((uint32_t)s) << 16;
  return v.f;
}
__device__ __forceinline__ uint32_t pkbf16(float lo, float hi) {
  uint32_t w;
  asm("v_cvt_pk_bf16_f32 %0, %1, %2" : "=v"(w) : "v"(lo), "v"(hi));
  return w;
}
// Fast exp2 via native v_exp_f32.  R10 LESSON: raw inline-asm v_exp_f32 has
// a TRANS->VALU dependent-use hazard the compiler does NOT guard for asm.
// Prefer the builtin; asm fallback carries its own s_nop.
__device__ __forceinline__ float fast_exp2(float x) {
#if __has_builtin(__builtin_amdgcn_exp2f)
  return __builtin_amdgcn_exp2f(x);
#else
  float r;
  asm("v_exp_f32 %0, %1\n\ts_nop 1" : "=v"(r) : "v"(x));
  return r;
#endif
}

// ---------------------------------------------------------------------------
// 1) fp32 -> bf16 conversion of x and the four weights; ALSO generates the
//    RoPE cos/sin table (2048 x 32 float2, 512 KB).  2048 blocks x 4-iter
//    grid-stride.
// ---------------------------------------------------------------------------
__global__ __launch_bounds__(256) void cvt_all_k(
    const float* __restrict__ x,  const float* __restrict__ wq,
    const float* __restrict__ wk, const float* __restrict__ wv,
    const float* __restrict__ wo, ushort* __restrict__ dst,
    float2* __restrict__ tab) {
  for (int it = 0; it < 4; it++) {
    int i = (it * 2048 + blockIdx.x) * 256 + threadIdx.x;  // 2,097,152 total
    const float* src;
    if      (i < 1048576) src = x  + (size_t)i * 4;
    else if (i < 1310720) src = wq + (size_t)(i - 1048576) * 4;
    else if (i < 1572864) src = wk + (size_t)(i - 1310720) * 4;
    else if (i < 1835008) src = wv + (size_t)(i - 1572864) * 4;
    else                  src = wo + (size_t)(i - 1835008) * 4;
    float4 v = *(const float4*)src;
    ushort4 o;
    o.x = f2b(v.x); o.y = f2b(v.y); o.z = f2b(v.z); o.w = f2b(v.w);
    ((ushort4*)dst)[i] = o;

    if (i < 65536) {                               // rope table: s x dp
      int s = i >> 5, dp = i & 31;
      float inv = exp2f((float)dp * (-13.2877123795494f / 32.0f));
      float ang = (float)s * inv;
      float sn, cs;
      sincosf(ang, &sn, &cs);
      tab[i] = make_float2(cs, sn);
    }
  }
}

// ---------------------------------------------------------------------------
// 2) GEMM mainloop: C = A(MxK) * W(NxK)^T, 128x128 tile, BK=32, 4 waves (2x2).
//    R16 form: double-buffered LDS, single barrier per K-step, stage(next)
//    issued BEFORE compute -- loads progress under the MFMAs and other
//    resident blocks cover the remaining drain.
// ---------------------------------------------------------------------------
__device__ __forceinline__ void gemm_mainloop(
    const ushort* __restrict__ A, const ushort* __restrict__ W,
    int row0, int col0, ushort* lds, f32x4 acc[4][4]) {
  const int K = 1024;
  int tid = threadIdx.x;
  int lane = tid & 63, wid = tid >> 6;
  int wr = wid >> 1, wc = wid & 1;
  int lr = lane >> 4, lc = lane & 15;
  ushort* lA = lds;
  ushort* lB = lds + 8192;

  auto stage = [&](int buf, int k0) {
#pragma unroll
    for (int i = 0; i < 2; i++) {
      int idx = tid + i * 256;                       // 16B chunk id, 4 per row
      const ushort* ga = A + (size_t)(row0 + (idx >> 2)) * K + k0 + (idx & 3) * 8;
      __builtin_amdgcn_global_load_lds(AS1(ga),
          AS3(lA + buf * 4096 + (i * 256 + wid * 64) * 8), 16, 0, 0);
      const ushort* gb = W + (size_t)(col0 + (idx >> 2)) * K + k0 + (idx & 3) * 8;
      __builtin_amdgcn_global_load_lds(AS1(gb),
          AS3(lB + buf * 4096 + (i * 256 + wid * 64) * 8), 16, 0, 0);
    }
  };

  stage(0, 0);
  __syncthreads();
  int cur = 0;
  for (int k0 = 0; k0 < K; k0 += 32) {
    if (k0 + 32 < K) stage(cur ^ 1, k0 + 32);
    const ushort* a  = lA + cur * 4096;
    const ushort* bm = lB + cur * 4096;
    bf16x8 af[4], bfr[4];
#pragma unroll
    for (int m = 0; m < 4; m++)
      af[m] = *(const bf16x8*)(a + (wr * 64 + m * 16 + lc) * 32 + lr * 8);
#pragma unroll
    for (int n = 0; n < 4; n++)
      bfr[n] = *(const bf16x8*)(bm + (wc * 64 + n * 16 + lc) * 32 + lr * 8);
#pragma unroll
    for (int m = 0; m < 4; m++)
#pragma unroll
      for (int n = 0; n < 4; n++)
        acc[m][n] = __builtin_amdgcn_mfma_f32_16x16x32_bf16(af[m], bfr[n], acc[m][n], 0, 0, 0);
    __syncthreads();     // drains: my ds_reads + next-buffer gload_lds writes
    cur ^= 1;
  }
}

// QKV projections in one launch (z = 0:Q, 1:K, 2:V).
// Q,K -> [B,H,S,D] with FUSED ROPE (rotation pair (d, d+32) lives in the
// same thread: acc[m][n] and acc[m][n+2] for n<2); Q scaled by 0.125*log2e
// so attention scores are natively exp2-domain.  cos/sin from tab (L2).
// V -> [B,H,D,S] via XOR-swizzled LDS transpose.
__global__ __launch_bounds__(256) void gemm_qkv_k(
    const ushort* __restrict__ xb,
    const ushort* __restrict__ wqb, const ushort* __restrict__ wkb,
    const ushort* __restrict__ wvb,
    const float2* __restrict__ tab,
    ushort* __restrict__ Qb, ushort* __restrict__ Kb, ushort* __restrict__ Vtb) {
  __shared__ ushort lds[16384];        // 32 KiB: dbuf staging, then V scratch
  int z = blockIdx.z;
  const ushort* w = (z == 0) ? wqb : (z == 1) ? wkb : wvb;
  int row0 = blockIdx.x * 128, col0 = blockIdx.y * 128;
  f32x4 acc[4][4] = {};
  gemm_mainloop(xb, w, row0, col0, lds, acc);

  int tid = threadIdx.x, lane = tid & 63, wid = tid >> 6;
  int wr = wid >> 1, wc = wid & 1, lr = lane >> 4, lc = lane & 15;

  if (z < 2) {
    ushort* dst = (z == 0) ? Qb : Kb;
    const float qs = (z == 0) ? 0.125f * 1.44269504088896f : 1.0f;
#pragma unroll
    for (int m = 0; m < 4; m++)
#pragma unroll
      for (int n = 0; n < 2; n++)
#pragma unroll
        for (int j = 0; j < 4; j++) {
          int i = row0 + wr * 64 + m * 16 + lr * 4 + j;   // row: b,s
          int c = col0 + wc * 64 + n * 16 + lc;           // col: h,d (d<32)
          int b = i >> 11, s = i & 2047, h = c >> 6, dp = c & 31;
          float2 cs = tab[s * 32 + dp];
          float q1 = acc[m][n][j], q2 = acc[m][n + 2][j];
          float r1 = (q1 * cs.x - q2 * cs.y) * qs;
          float r2 = (q2 * cs.x + q1 * cs.y) * qs;
          size_t base = (size_t)(b * 16 + h) * 131072 + (size_t)s * 64;
          dst[base + dp]      = f2b(r1);
          dst[base + dp + 32] = f2b(r2);
        }
  } else {
    // V: transpose 128x128 tile through LDS (free after final barrier).
#pragma unroll
    for (int m = 0; m < 4; m++)
#pragma unroll
      for (int n = 0; n < 4; n++) {
        int c = wc * 64 + n * 16 + lc;
        int sb = wr * 64 + m * 16 + lr * 4;            // j=0..3 consecutive
        uint32_t w0 = pkbf16(acc[m][n][0], acc[m][n][1]);
        uint32_t w1 = pkbf16(acc[m][n][2], acc[m][n][3]);
        int soff = sb ^ ((c & 7) << 3);                // multiple of 4 ushorts
        uint2 val; val.x = w0; val.y = w1;
        *(uint2*)(lds + c * 128 + soff) = val;         // 8B store
      }
    __syncthreads();
    int b = row0 >> 11, srow = row0 & 2047;
#pragma unroll
    for (int i = 0; i < 8; i++) {
      int idx = i * 256 + tid;                 // 2048 16B chunks
      int cl = idx >> 4, sc = idx & 15;
      int soff = (sc * 8) ^ ((cl & 7) << 3);
      bf16x8 v = *(const bf16x8*)(lds + cl * 128 + soff);
      int cg = col0 + cl, h = cg >> 6, d = cg & 63;
      *(bf16x8*)(Vtb + (size_t)(b * 16 + h) * 131072 + (size_t)d * 2048 + srow + sc * 8) = v;
    }
  }
}

// Final projection: out(fp32) = attn @ Wo^T.  128x64 tile, 512 blocks
// (2 blocks/CU), R16 single-barrier dbuf form.
__global__ __launch_bounds__(256) void gemm_out_k(
    const ushort* __restrict__ Ab, const ushort* __restrict__ wob,
    float* __restrict__ out) {
  __shared__ ushort lds[12288];   // lA dbuf 2x[128][32], lB dbuf 2x[64][32]
  const int K = 1024;
  int tid = threadIdx.x, lane = tid & 63, wid = tid >> 6;
  int lr = lane >> 4, lc = lane & 15;
  int row0 = blockIdx.x * 128, col0 = blockIdx.y * 64;
  ushort* lA = lds;
  ushort* lB = lds + 8192;

  auto stage = [&](int buf, int k0) {
#pragma unroll
    for (int i = 0; i < 2; i++) {
      int idx = tid + i * 256;                       // A: 512 chunks, 4/row
      const ushort* ga = Ab + (size_t)(row0 + (idx >> 2)) * K + k0 + (idx & 3) * 8;
      __builtin_amdgcn_global_load_lds(AS1(ga),
          AS3(lA + buf * 4096 + (i * 256 + wid * 64) * 8), 16, 0, 0);
    }
    const ushort* gb = wob + (size_t)(col0 + (tid >> 2)) * K + k0 + (tid & 3) * 8;
    __builtin_amdgcn_global_load_lds(AS1(gb),
        AS3(lB + buf * 2048 + wid * 512), 16, 0, 0);
  };

  f32x4 acc[2][4] = {};
  stage(0, 0);
  __syncthreads();
  int cur = 0;
  for (int k0 = 0; k0 < K; k0 += 32) {
    if (k0 + 32 < K) stage(cur ^ 1, k0 + 32);
    const ushort* a  = lA + cur * 4096;
    const ushort* bm = lB + cur * 2048;
    bf16x8 af[2], bfr[4];
#pragma unroll
    for (int m = 0; m < 2; m++)
      af[m] = *(const bf16x8*)(a + (wid * 32 + m * 16 + lc) * 32 + lr * 8);
#pragma unroll
    for (int n = 0; n < 4; n++)
      bfr[n] = *(const bf16x8*)(bm + (n * 16 + lc) * 32 + lr * 8);
#pragma unroll
    for (int m = 0; m < 2; m++)
#pragma unroll
      for (int n = 0; n < 4; n++)
        acc[m][n] = __builtin_amdgcn_mfma_f32_16x16x32_bf16(af[m], bfr[n], acc[m][n], 0, 0, 0);
    __syncthreads();
    cur ^= 1;
  }

  int base_r = row0 + wid * 32;
#pragma unroll
  for (int m = 0; m < 2; m++)
#pragma unroll
    for (int n = 0; n < 4; n++)
#pragma unroll
      for (int j = 0; j < 4; j++) {
        int i = base_r + m * 16 + lr * 4 + j;
        int c = col0 + n * 16 + lc;
        out[(size_t)i * 1024 + c] = acc[m][n][j];
      }
}

// ---------------------------------------------------------------------------
// 3) Flash attention, 32x32 swapped-QK + within-block KV-split + counted
//    vmcnt pipeline + intra-iteration MFMA/VALU interleave.
// ---------------------------------------------------------------------------
__global__ __launch_bounds__(512, 4) void attn_k(
    const ushort* __restrict__ Qb, const ushort* __restrict__ Kb,
    const ushort* __restrict__ Vtb, ushort* __restrict__ Ob) {
  __shared__ char ldsb[65536];   // [buf:2][tile:2][K 8KB | V 8KB]; reused
  int tid = threadIdx.x, lane = tid & 63, wid = tid >> 6;   // wid in [0,8)
  int lc5 = lane & 31, hi = lane >> 5;
  int qsub = wid & 3, grp = wid >> 2;

  // XCD swizzle: all q-tiles of a head on one XCD
  int bid = blockIdx.x;
  int qt = (bid >> 3) & 15;
  int bh = (bid & 7) + ((bid >> 7) << 3);
  int q0 = qt * 128 + qsub * 32;
  const ushort* Qp = Qb  + (size_t)bh * 131072 + (size_t)q0 * 64;
  const ushort* Kp = Kb  + (size_t)bh * 131072;
  const ushort* Vp = Vtb + (size_t)bh * 131072;

  // Q as B-operand: col = q = lc5, k-dim = d: slice ks -> d = ks*16+8*hi+i
  bf16x8 qf[4];
#pragma unroll
  for (int ks = 0; ks < 4; ks++)
    qf[ks] = *(const bf16x8*)(Qp + lc5 * 64 + ks * 16 + hi * 8);

  f32x16 o0, o1;
#pragma unroll
  for (int i = 0; i < 16; i++) { o0[i] = 0.f; o1[i] = 0.f; }
  float lsum = 0.f;

  // swizzled in-row chunk offsets: chunk(ks) = (2ks+hi) ^ (row&7), row&7=lc5&7
  int swz[4];
#pragma unroll
  for (int ks = 0; ks < 4; ks++)
    swz[ks] = (((2 * ks + hi) ^ (lc5 & 7)) << 4);
  const int rbase = lc5 * 128;

  // stage the 128-key pair [kvp, kvp+128) into buf: tile t = keys
  // [kvp+64t, kvp+64t+64).  4 gload_lds per thread per call.
  auto stage = [&](int buf, int kvp) {
    int r = tid >> 3, cp = tid & 7;
    int ubase = wid * 1024;
#pragma unroll
    for (int t = 0; t < 2; t++) {
      char* tb = ldsb + buf * 32768 + t * 16384;
      const ushort* gk = Kp + (size_t)(kvp + 64 * t + r) * 64 + ((cp ^ (r & 7)) << 3);
      __builtin_amdgcn_global_load_lds(AS1(gk), AS3(tb + ubase), 16, 0, 0);
      const ushort* gv = Vp + (size_t)r * 2048 + kvp + 64 * t + ((cp ^ (r & 7)) << 3);
      __builtin_amdgcn_global_load_lds(AS1(gv), AS3(tb + 8192 + ubase), 16, 0, 0);
    }
  };

  // softmax + pack one 32-key half: exp2, row-sum accumulate, -> 2 A-frags
  auto smpack = [&](f32x16& s, bf16x8* aout) {
#pragma unroll
    for (int i = 0; i < 16; i++) s[i] = fast_exp2(s[i]);
    float acc = 0.f;
#pragma unroll
    for (int i = 0; i < 16; i++) acc += s[i];
    lsum += acc;
#pragma unroll
    for (int h2 = 0; h2 < 2; h2++) {
      int rb = 8 * h2;
      uint32_t wa1 = pkbf16(s[rb],     s[rb + 1]);
      uint32_t wb1 = pkbf16(s[rb + 4], s[rb + 5]);
      asm("v_permlane32_swap_b32 %0, %1" : "+v"(wa1), "+v"(wb1));
      uint32_t wa2 = pkbf16(s[rb + 2], s[rb + 3]);
      uint32_t wb2 = pkbf16(s[rb + 6], s[rb + 7]);
      asm("v_permlane32_swap_b32 %0, %1" : "+v"(wa2), "+v"(wb2));
      union { uint32_t u[4]; bf16x8 v; } tmp;
      tmp.u[0] = wa1; tmp.u[1] = wa2; tmp.u[2] = wb1; tmp.u[3] = wb2;
      aout[h2] = tmp.v;
    }
  };

  stage(0, 0);      // pair 0 -> buf 0   (4 loads)
  stage(1, 128);    // pair 1 -> buf 1   (4 loads)
  int cur = 0;

  for (int kvp = 0; kvp < 2048; kvp += 128) {
    // wait MY pair-p loads (oldest 4); keep pair-(p+1)'s 4 in flight
    if (kvp + 128 < 2048) asm volatile("s_waitcnt vmcnt(4)" ::: "memory");
    else                  asm volatile("s_waitcnt vmcnt(0)" ::: "memory");
    asm volatile("s_barrier" ::: "memory");   // pair-p writes visible block-wide

    const char* kbuf = ldsb + cur * 32768 + grp * 16384;   // my tile
    const char* vbuf = kbuf + 8192;

    // --- QK chains: s0 fully first, then s1 (independent chains) ---
    f32x16 s0 = {}, s1 = {};
    __builtin_amdgcn_s_setprio(1);
#pragma unroll
    for (int ks = 0; ks < 4; ks++) {
      bf16x8 ka0 = *(const bf16x8*)(kbuf + rbase + swz[ks]);
      s0 = __builtin_amdgcn_mfma_f32_32x32x16_bf16(ka0, qf[ks], s0, 0, 0, 0);
    }
#pragma unroll
    for (int ks = 0; ks < 4; ks++) {
      bf16x8 ka1 = *(const bf16x8*)(kbuf + 4096 + rbase + swz[ks]);
      s1 = __builtin_amdgcn_mfma_f32_32x32x16_bf16(ka1, qf[ks], s1, 0, 0, 0);
    }
    __builtin_amdgcn_s_setprio(0);

    // --- softmax(s0): VALU overlaps s1's in-flight MFMAs ---
    bf16x8 a01[2], a23[2];
    smpack(s0, a01);

    // --- PV ks=0,1 (uses only a01): MFMA overlaps softmax(s1) below ---
    __builtin_amdgcn_s_setprio(1);
#pragma unroll
    for (int ks = 0; ks < 2; ks++) {
      bf16x8 vb0 = *(const bf16x8*)(vbuf + rbase + swz[ks]);
      bf16x8 vb1 = *(const bf16x8*)(vbuf + 4096 + rbase + swz[ks]);
      o0 = __builtin_amdgcn_mfma_f32_32x32x16_bf16(a01[ks], vb0, o0, 0, 0, 0);
      o1 = __builtin_amdgcn_mfma_f32_32x32x16_bf16(a01[ks], vb1, o1, 0, 0, 0);
    }
    __builtin_amdgcn_s_setprio(0);

    // --- softmax(s1): VALU overlaps PV ks=0,1 ---
    smpack(s1, a23);

    // --- PV ks=2,3 ---
    __builtin_amdgcn_s_setprio(1);
#pragma unroll
    for (int ks = 2; ks < 4; ks++) {
      bf16x8 vb0 = *(const bf16x8*)(vbuf + rbase + swz[ks]);
      bf16x8 vb1 = *(const bf16x8*)(vbuf + 4096 + rbase + swz[ks]);
      o0 = __builtin_amdgcn_mfma_f32_32x32x16_bf16(a23[ks - 2], vb0, o0, 0, 0, 0);
      o1 = __builtin_amdgcn_mfma_f32_32x32x16_bf16(a23[ks - 2], vb1, o1, 0, 0, 0);
    }
    __builtin_amdgcn_s_setprio(0);

    asm volatile("s_barrier" ::: "memory");   // all waves done reading buf cur
    if (kvp + 256 < 2048) stage(cur, kvp + 256);   // overwrite freed buffer
    cur ^= 1;
  }

  // combine the two kv-halves: group 1 writes partials, group 0 adds.
  // stride 33 floats (odd) -> conflict-free.  ldsb free: vmcnt drained at
  // last iter, all reads done at its trailing barrier.
  float* cb = (float*)ldsb;
  float* p = cb + (size_t)(qsub * 64 + lane) * 33;
  if (grp == 1) {
#pragma unroll
    for (int i = 0; i < 16; i++) { p[i] = o0[i]; p[16 + i] = o1[i]; }
    p[32] = lsum;
  }
  __syncthreads();
  if (grp == 0) {
#pragma unroll
    for (int i = 0; i < 16; i++) { o0[i] += p[i]; o1[i] += p[16 + i]; }
    lsum += p[32];

    // combine the two key-halves of lsum (lanes q and q+32), then normalize
    lsum += __shfl_xor(lsum, 32);
    float invq = 1.0f / lsum;
    float invr[16];
#pragma unroll
    for (int r = 0; r < 16; r++)
      invr[r] = __shfl(invq, (r & 3) + 8 * (r >> 2) + 4 * hi);

    int b = bh >> 4, h = bh & 15;
    ushort* Op = Ob + (size_t)(b * 2048 + q0) * 1024 + h * 64 + lc5;
#pragma unroll
    for (int r = 0; r < 16; r++) {
      int rrow = (r & 3) + 8 * (r >> 2) + 4 * hi;
      Op[(size_t)rrow * 1024]      = f2b(o0[r] * invr[r]);
      Op[(size_t)rrow * 1024 + 32] = f2b(o1[r] * invr[r]);
    }
  }
}

// ---------------------------------------------------------------------------
// Workspace layout: xb 8M | wqb/wkb/wvb/wob 2M each | Qb 8M | Kb 8M | Vtb 8M
// | Ob 8M  (total 48 MiB).  The rope cos/sin table (512 KB) borrows the
// head of the Ob region: alive only cvt->qkv; attn overwrites it later.
// ---------------------------------------------------------------------------
extern "C" void kernel_launch(void* const* d_in, const int* in_sizes, int n_in,
                              void* d_out, int out_size, void* d_ws, size_t ws_size,
                              hipStream_t stream) {
  const float* x  = (const float*)d_in[0];
  const float* wq = (const float*)d_in[1];
  const float* wk = (const float*)d_in[2];
  const float* wv = (const float*)d_in[3];
  const float* wo = (const float*)d_in[4];
  float* out = (float*)d_out;
  char* ws = (char*)d_ws;
  const size_t MiB = 1024 * 1024;
  ushort* xb  = (ushort*)(ws + 0);
  ushort* wqb = (ushort*)(ws + 8 * MiB);
  ushort* wkb = (ushort*)(ws + 10 * MiB);
  ushort* wvb = (ushort*)(ws + 12 * MiB);
  ushort* wob = (ushort*)(ws + 14 * MiB);
  ushort* Qb  = (ushort*)(ws + 16 * MiB);
  ushort* Kb  = (ushort*)(ws + 24 * MiB);
  ushort* Vtb = (ushort*)(ws + 32 * MiB);
  ushort* Ob  = (ushort*)(ws + 40 * MiB);
  float2* tab = (float2*)Ob;                 // 65536 * 8B = 512 KB, transient

  cvt_all_k<<<2048, 256, 0, stream>>>(x, wq, wk, wv, wo, xb, tab);
  dim3 gqkv(32, 8, 3);
  gemm_qkv_k<<<gqkv, 256, 0, stream>>>(xb, wqb, wkb, wvb, tab, Qb, Kb, Vtb);
  attn_k<<<512, 512, 0, stream>>>(Qb, Kb, Vtb, Ob);
  dim3 gout(32, 16);
  gemm_out_k<<<gout, 256, 0, stream>>>(Ob, wob, out);
}